// Round 5
// baseline (132.543 us; speedup 1.0000x reference)
//
#include <hip/hip_runtime.h>
#include <cstddef>

// Problem constants: BS=16, Q=900, NC=91, M=1600
#define NROWS 14400          // BS*Q
#define NCLS  91
#define MTGT  1600
#define NG    400            // float4 column-groups per row (1600/4)
#define RPT   4              // rows per thread
#define CPT   4              // cols per thread (one float4)
#define TPB   256
#define TBL   (NROWS * NCLS)                  // 1,310,400
#define NTHREADS ((NROWS / RPT) * NG)         // 1,440,000
#define PREP_BLOCKS ((TBL + TPB - 1) / TPB)   // 5120
#define PAIR_BLOCKS (NTHREADS / TPB)          // 5625 exact

// native vector type for nontemporal store (HIP float4 is a class -> rejected)
typedef float fx4 __attribute__((ext_vector_type(4)));

// ---- Kernel A: focal classification cost table -> workspace ----
// cc[row*91 + c] = pos - neg + 1.0   (+1 folds GIoU's constant:
//   C = l1 + cc + 1 - inter/uni - uni/ea)
__global__ __launch_bounds__(TPB) void prep_kernel(
    const float* __restrict__ logits, float* __restrict__ cc)
{
    const int gid = blockIdx.x * TPB + threadIdx.x;
    if (gid >= TBL) return;
    const float x = logits[gid];
    const float p = 1.0f / (1.0f + __expf(-x));
    const float omp = 1.0f - p;
    const float neg = 0.75f * p * p * (-log1pf(-p + 1e-8f));
    const float pos = 0.25f * omp * omp * (-logf(p + 1e-8f));
    cc[gid] = pos - neg + 1.0f;
}

// ---- Kernel B: pairwise cost; 1 thread = 4 rows x 4 cols = 16 outputs ----
__global__ __launch_bounds__(TPB) void pair_kernel(
    const float* __restrict__ boxes,   // [NROWS,4] cxcywh
    const int*   __restrict__ tids,    // [MTGT]
    const float* __restrict__ tbox,    // [MTGT,4] cxcywh
    const float* __restrict__ cc,      // [NROWS,NCLS] (+1 folded)
    float*       __restrict__ out)     // [NROWS,MTGT]
{
    const int gid = blockIdx.x * TPB + threadIdx.x;   // < 1,440,000
    const int rq  = gid / NG;                         // row-quad [0,3600)
    const int g   = gid - rq * NG;                    // col-group [0,400)
    const int row0 = rq * RPT;

    // 4 pred rows: raw cxcywh (for L1) + xyxy + area
    float pcx[RPT], pcy[RPT], pw[RPT], ph[RPT];
    float px0[RPT], py0[RPT], px1[RPT], py1[RPT], pa[RPT];
    const float4* bx4 = reinterpret_cast<const float4*>(boxes);
#pragma unroll
    for (int k = 0; k < RPT; ++k) {
        const float4 p = bx4[row0 + k];   // near-uniform in wave -> L1 broadcast
        pcx[k] = p.x; pcy[k] = p.y; pw[k] = p.z; ph[k] = p.w;
        px0[k] = p.x - 0.5f * p.z;  px1[k] = p.x + 0.5f * p.z;
        py0[k] = p.y - 0.5f * p.w;  py1[k] = p.y + 0.5f * p.w;
        pa[k]  = p.z * p.w;
    }

    const int4 idv = reinterpret_cast<const int4*>(tids)[g];
    const int ida[CPT] = { idv.x, idv.y, idv.z, idv.w };
    const float4* tb4 = reinterpret_cast<const float4*>(tbox);

    float res[RPT][CPT];   // all indices compile-time -> registers
#pragma unroll
    for (int j = 0; j < CPT; ++j) {
        const float4 tb = tb4[g * CPT + j];           // coalesced 16B
        const float tx0 = tb.x - 0.5f * tb.z, tx1 = tb.x + 0.5f * tb.z;
        const float ty0 = tb.y - 0.5f * tb.w, ty1 = tb.y + 0.5f * tb.w;
        const float ta  = tb.z * tb.w;
        const int   id  = ida[j];
#pragma unroll
        for (int k = 0; k < RPT; ++k) {
            const float ccv = cc[(size_t)(row0 + k) * NCLS + id]; // L1 gather
            const float l1 = fabsf(pcx[k] - tb.x) + fabsf(pcy[k] - tb.y)
                           + fabsf(pw[k]  - tb.z) + fabsf(ph[k]  - tb.w);
            const float iw = fminf(px1[k], tx1) - fmaxf(px0[k], tx0);
            const float ih = fminf(py1[k], ty1) - fmaxf(py0[k], ty0);
            const float inter = fmaxf(iw, 0.0f) * fmaxf(ih, 0.0f);
            const float uni = pa[k] + ta - inter;
            const float ew = fmaxf(px1[k], tx1) - fminf(px0[k], tx0);
            const float eh = fmaxf(py1[k], ty1) - fminf(py0[k], ty0);
            const float ea = ew * eh;
            // giou = inter/uni + uni/ea - 1 -> one rcp:
            const float num  = fmaf(inter, ea, uni * uni);
            const float rden = __builtin_amdgcn_rcpf(uni * ea);
            res[k][j] = l1 + ccv - num * rden;        // ccv includes +1
        }
    }

    fx4* out4 = reinterpret_cast<fx4*>(out);
#pragma unroll
    for (int k = 0; k < RPT; ++k) {
        const fx4 o = { res[k][0], res[k][1], res[k][2], res[k][3] };
        // streaming 92MB output: nontemporal hint, wave-contiguous 1KB/row
        __builtin_nontemporal_store(o, &out4[(size_t)(row0 + k) * NG + g]);
    }
}

extern "C" void kernel_launch(void* const* d_in, const int* in_sizes, int n_in,
                              void* d_out, int out_size, void* d_ws, size_t ws_size,
                              hipStream_t stream) {
    const float* logits = (const float*)d_in[0];
    const float* boxes  = (const float*)d_in[1];
    const int*   tids   = (const int*)d_in[2];
    const float* tbox   = (const float*)d_in[3];
    float* outp = (float*)d_out;
    float* cc   = (float*)d_ws;   // 5,241,600 B class-cost table

    hipLaunchKernelGGL(prep_kernel, dim3(PREP_BLOCKS), dim3(TPB), 0, stream,
                       logits, cc);
    hipLaunchKernelGGL(pair_kernel, dim3(PAIR_BLOCKS), dim3(TPB), 0, stream,
                       boxes, tids, tbox, cc, outp);
}